// Round 19
// baseline (486.899 us; speedup 1.0000x reference)
//
#include <hip/hip_runtime.h>
#include <cstdint>
#include <cstddef>

#define N_NODES 50000
#define HDIM 64
#define NREL 50
#define NEDGE 800000
#define DCHUNK 196    // ceil(N_NODES/256)
#define CHUNKSH 11    // 2048 dsts per csort chunk
#define NCHUNK 25
#define SUBSH 6       // 64 dsts per subchunk (fuse granule)
#define NSUB 782      // ceil(50000/64)
#define NKEY2 (NCHUNK * 2048)   // key space: chunk*2048 + sub*64 + rel (holes at rel>=50)
#define KCH2 200      // keys per thread in kscan (256*200 = 51200)
#define CAP 36864     // arena capacity per chunk
#define TILE 8192     // edges per msplit/place block
#define SCRP 40       // transpose scratch row stride (elems): 80 B, 16B-aligned

typedef __attribute__((ext_vector_type(8))) short short8;
typedef __attribute__((ext_vector_type(4))) float f32x4;

static __device__ __forceinline__ unsigned short f2bf(float f) {
  union { float f; unsigned int u; } v; v.f = f;
  unsigned int u = v.u;
  unsigned int r = (u + 0x7FFFu + ((u >> 16) & 1u)) >> 16;  // RNE
  return (unsigned short)r;
}

// ---- preprocessing (verified in r14): two-level sort by (sub64, rel) ------

__global__ __launch_bounds__(256) void csort_k(const int* __restrict__ ei,
                                               const int* __restrict__ et,
                                               int* __restrict__ ccur,
                                               int2* __restrict__ ce) {
  __shared__ int chist[32];
  __shared__ int cbase[32];
  int tid = threadIdx.x;
  if (tid < 32) chist[tid] = 0;
  __syncthreads();
  int ebase = blockIdx.x * 1280 + tid;          // 625 blocks x 1280 edges
  int src_[5], dr_[5], ch_[5], loc_[5];
#pragma unroll
  for (int i = 0; i < 5; ++i) {
    int e = ebase + i * 256;
    int src = ei[e];
    int dst = ei[NEDGE + e];
    int r = et[e];
    int ch = dst >> CHUNKSH;
    src_[i] = src;
    dr_[i] = (dst << 6) | r;
    ch_[i] = ch;
    loc_[i] = atomicAdd(&chist[ch], 1);         // LDS
  }
  __syncthreads();
  if (tid < NCHUNK && chist[tid] > 0)
    cbase[tid] = atomicAdd(&ccur[tid], chist[tid]);   // 25 returning/block
  __syncthreads();
#pragma unroll
  for (int i = 0; i < 5; ++i)
    ce[(size_t)ch_[i] * CAP + cbase[ch_[i]] + loc_[i]] = make_int2(src_[i], dr_[i]);
}

// per (chunk, tile): multisplit over 2048 dsts and 2048 (sub,rel) keys
__global__ __launch_bounds__(1024) void msplit_k(const int2* __restrict__ ce,
                                                 const int* __restrict__ ccur,
                                                 int* __restrict__ dcur,
                                                 int* __restrict__ kcur,
                                                 int* __restrict__ dkr) {
  __shared__ int dhist[2048], dbase[2048];
  __shared__ int khist[2048], kbs[2048];
  int c = blockIdx.y;
  int len = ccur[c];
  int t0 = blockIdx.x * TILE;
  if (t0 >= len) return;                        // block-uniform
  int tid = threadIdx.x;
  dhist[tid] = 0; dhist[tid + 1024] = 0;
  khist[tid] = 0; khist[tid + 1024] = 0;
  __syncthreads();
  int n = min(TILE, len - t0);
  const int2* seg = ce + (size_t)c * CAP + t0;
  int pk[8], dr_[8];
#pragma unroll
  for (int k = 0; k < 8; ++k) {
    int j = tid + k * 1024;
    if (j < n) {
      int2 v = seg[j];
      dr_[k] = v.y;
      int d11 = (v.y >> 6) & 2047;
      int rel = v.y & 63;
      int kl = ((d11 >> SUBSH) << 6) | rel;     // sub(0..31)*64 + rel
      int dl = atomicAdd(&dhist[d11], 1);       // LDS
      int rl = atomicAdd(&khist[kl], 1);        // LDS
      pk[k] = (dl << 16) | rl;
    } else {
      pk[k] = -1;
    }
  }
  __syncthreads();
  int h;
  h = dhist[tid];        if (h > 0) dbase[tid] = atomicAdd(&dcur[(c << CHUNKSH) + tid], h);
  h = dhist[tid + 1024]; if (h > 0) dbase[tid + 1024] = atomicAdd(&dcur[(c << CHUNKSH) + tid + 1024], h);
  h = khist[tid];        if (h > 0) kbs[tid] = atomicAdd(&kcur[c * 2048 + tid], h);
  h = khist[tid + 1024]; if (h > 0) kbs[tid + 1024] = atomicAdd(&kcur[c * 2048 + tid + 1024], h);
  __syncthreads();
#pragma unroll
  for (int k = 0; k < 8; ++k) {
    if (pk[k] >= 0) {
      int d11 = (dr_[k] >> 6) & 2047;
      int rel = dr_[k] & 63;
      int kl = ((d11 >> SUBSH) << 6) | rel;
      int drank = dbase[d11] + (pk[k] >> 16);
      int krank = kbs[kl] + (pk[k] & 0xFFFF);
      dkr[(size_t)c * CAP + t0 + tid + k * 1024] = (drank << 16) | krank;
    }
  }
}

// scan of kcur (51200 key counts, holes=0) -> key_off
__global__ __launch_bounds__(256) void kscan_k(const int* __restrict__ kcur,
                                               int* __restrict__ key_off) {
  __shared__ int a[256], bb[256];
  int t = threadIdx.x;
  int base = t * KCH2;
  int s = 0;
  for (int i = 0; i < KCH2; ++i) s += kcur[base + i];
  a[t] = s;
  __syncthreads();
  bool flip = false;
  for (int off = 1; off < 256; off <<= 1) {
    int* c = flip ? bb : a;
    int* n = flip ? a : bb;
    int x = c[t];
    if (t >= off) x += c[t - off];
    n[t] = x;
    __syncthreads();
    flip = !flip;
  }
  int incl = (flip ? bb : a)[t];
  int run = incl - s;
  for (int i = 0; i < KCH2; ++i) {
    key_off[base + i] = run;
    run += kcur[base + i];
  }
  if (t == 255) key_off[NKEY2] = incl;          // == NEDGE
}

__global__ __launch_bounds__(256) void dsA_k(const int* __restrict__ dcnt,
                                             int* __restrict__ psum) {
  __shared__ int red[256];
  int t = threadIdx.x, b = blockIdx.x;
  int idx = b * DCHUNK + t;
  int v = (t < DCHUNK && idx < N_NODES) ? dcnt[idx] : 0;
  red[t] = v;
  __syncthreads();
  for (int s = 128; s > 0; s >>= 1) {
    if (t < s) red[t] += red[t + s];
    __syncthreads();
  }
  if (t == 0) psum[b] = red[0];
}

__global__ __launch_bounds__(256) void dsB_k(const int* __restrict__ psum,
                                             int* __restrict__ psb,
                                             int* __restrict__ dst_off) {
  __shared__ int a[256], bb[256];
  int t = threadIdx.x;
  int v = psum[t];
  a[t] = v;
  __syncthreads();
  bool flip = false;
  for (int off = 1; off < 256; off <<= 1) {
    int* c = flip ? bb : a;
    int* n = flip ? a : bb;
    int x = c[t];
    if (t >= off) x += c[t - off];
    n[t] = x;
    __syncthreads();
    flip = !flip;
  }
  int incl = (flip ? bb : a)[t];
  psb[t] = incl - v;
  if (t == 255) dst_off[N_NODES] = incl;
}

__global__ __launch_bounds__(256) void dsC_k(const int* __restrict__ dcnt,
                                             const int* __restrict__ psb,
                                             int* __restrict__ dst_off) {
  __shared__ int a[256], bb[256];
  int t = threadIdx.x, b = blockIdx.x;
  int idx = b * DCHUNK + t;
  int v = (t < DCHUNK && idx < N_NODES) ? dcnt[idx] : 0;
  a[t] = v;
  __syncthreads();
  bool flip = false;
  for (int off = 1; off < 256; off <<= 1) {
    int* c = flip ? bb : a;
    int* n = flip ? a : bb;
    int x = c[t];
    if (t >= off) x += c[t - off];
    n[t] = x;
    __syncthreads();
    flip = !flip;
  }
  int incl = (flip ? bb : a)[t];
  if (t < DCHUNK && idx < N_NODES) dst_off[idx] = psb[b] + (incl - v);
}

// final placement: es/dl8 in (sub,rel)-key order; rpr in dst order (for coef)
__global__ __launch_bounds__(1024) void place_k(const int2* __restrict__ ce,
                                                const int* __restrict__ ccur,
                                                const int* __restrict__ dkr,
                                                const int* __restrict__ key_off,
                                                const int* __restrict__ dst_off,
                                                int* __restrict__ es,
                                                unsigned char* __restrict__ dl8,
                                                int* __restrict__ rpr) {
  int c = blockIdx.y;
  int len = ccur[c];
  int t0 = blockIdx.x * TILE;
  if (t0 >= len) return;
  int tid = threadIdx.x;
  int n = min(TILE, len - t0);
  size_t base = (size_t)c * CAP + t0;
#pragma unroll
  for (int k = 0; k < 8; ++k) {
    int j = tid + k * 1024;
    if (j < n) {
      int2 v = ce[base + j];
      int dk = dkr[base + j];
      int dst = v.y >> 6;
      int rel = v.y & 63;
      int key = c * 2048 + ((((dst >> SUBSH) & 31)) << 6) + rel;
      int pos = key_off[key] + (dk & 0xFFFF);
      int dp = dst_off[dst] + (dk >> 16);
      es[pos] = v.x;
      dl8[pos] = (unsigned char)(dst & 63);
      rpr[dp] = (pos << 6) | rel;
    }
  }
}

// cmeta[pos] = (bf16(1/count) << 16) | dst_local6  -- indicator-MFMA metadata
__global__ __launch_bounds__(256) void coef_k(const int* __restrict__ rpr,
                                              const unsigned char* __restrict__ dl8,
                                              const int* __restrict__ dst_off,
                                              int* __restrict__ cmeta) {
  int lane = threadIdx.x & 63;
  int wv = (blockIdx.x * 256 + threadIdx.x) >> 6;
  int half = lane >> 5, l = lane & 31;
  int dst = wv * 2 + half;
  if (dst >= N_NODES) return;
  int lo = dst_off[dst], hi = dst_off[dst + 1];
  for (int j = lo + l; j < hi; j += 32) {
    int r = rpr[j] & 63;
    int c = 0;
    for (int k = lo; k < hi; ++k) c += ((rpr[k] & 63) == r);
    int pos = rpr[j] >> 6;
    cmeta[pos] = ((int)f2bf(1.0f / (float)c) << 16) | (int)dl8[pos];
  }
}

// weight prep: transpose to [r][o][d] bf16; expand block-diagonal to dense
__global__ void prep_k(const float* __restrict__ w0, const float* __restrict__ w1,
                       const float* __restrict__ w2,
                       const float* __restrict__ wr0f, const float* __restrict__ wr1f,
                       const float* __restrict__ wr2f,
                       unsigned short* __restrict__ Wt0, unsigned short* __restrict__ Wt1,
                       unsigned short* __restrict__ Wt2,
                       unsigned short* __restrict__ Wr0, unsigned short* __restrict__ Wr1,
                       unsigned short* __restrict__ Wr2) {
  int idx = blockIdx.x * 256 + threadIdx.x;
  if (idx < NREL * 4096) {
    int r = idx >> 12, rem = idx & 4095, d = rem >> 6, o = rem & 63;
    int tpos = (r << 12) + (o << 6) + d;        // [r][o][d]
    Wt2[tpos] = f2bf(w2[idx]);                  // w2 is [r][d][o]
    int b = o >> 4;
    float v0 = 0.f, v1 = 0.f;
    if (b == (d >> 4)) {
      int widx = ((r * 4 + b) * 16 + (d & 15)) * 16 + (o & 15);
      v0 = w0[widx];
      v1 = w1[widx];
    }
    Wt0[tpos] = f2bf(v0);
    Wt1[tpos] = f2bf(v1);
  }
  if (idx < 4096) {
    int d = idx >> 6, o = idx & 63;
    int tpos = (o << 6) + d;
    Wr0[tpos] = f2bf(wr0f[idx]);
    Wr1[tpos] = f2bf(wr1f[idx]);
    Wr2[tpos] = f2bf(wr2f[idx]);
  }
}

// fp32 -> bf16 convert (layer-0 input only)
__global__ void conv_k(const float* __restrict__ in, unsigned short* __restrict__ out) {
  int i = blockIdx.x * 256 + threadIdx.x;
  out[i] = f2bf(in[i]);
}

// ---- fused per-layer kernel (atomic-free) ---------------------------------
// One block (4 waves) per 64-dst subchunk. Per 32-edge step: edge MFMAs
// (verified r11 layout) -> transpose via wave-private LDS -> indicator MFMAs
// accumulate D[dst16][dim] in registers (A = coef * [dl==gr*16+m] from cmeta).
// Cross-wave combine: 4 serialized register->LDS adds (uniform barriers).
// Epilogue fuses root GEMM + bias (+ReLU/bf16 or fp32 out).
__global__ __launch_bounds__(256) void fuse_k(const unsigned short* __restrict__ xin,
                                              const unsigned short* __restrict__ wt,
                                              const unsigned short* __restrict__ wrr,
                                              const float* __restrict__ bias,
                                              const int* __restrict__ es,
                                              const int* __restrict__ cmeta,
                                              const int* __restrict__ key_off,
                                              unsigned short* __restrict__ xout,
                                              float* __restrict__ outf,
                                              int mode) {
  __shared__ float accL[64 * 64];               // 16 KB
  __shared__ unsigned short scr[4][64 * SCRP];  // 4 x 5120 B = 20 KB
  int tid = threadIdx.x;
  int wv = tid >> 6, lane = tid & 63;
  int n15 = lane & 15, quad = lane >> 4;
  int g = blockIdx.x;
  int kbase = (g >> 5) * 2048 + (g & 31) * 64;
  unsigned short* ms = scr[wv];

  f32x4 D[4][4];                                // [dst-group][nb]
#pragma unroll
  for (int gr = 0; gr < 4; ++gr)
#pragma unroll
    for (int nb = 0; nb < 4; ++nb) D[gr][nb] = (f32x4){0.f, 0.f, 0.f, 0.f};

  for (int rel = wv; rel < NREL; rel += 4) {    // wave-uniform segments
    int lo = key_off[kbase + rel], hi = key_off[kbase + rel + 1];
    if (lo >= hi) continue;
    const unsigned short* wr = wt + ((size_t)rel << 12);
    short8 bfr[4][2];
#pragma unroll
    for (int nb = 0; nb < 4; ++nb)
#pragma unroll
      for (int k = 0; k < 2; ++k)
        bfr[nb][k] = *reinterpret_cast<const short8*>(wr + ((nb * 16 + n15) << 6) + k * 32 + quad * 8);

    for (int base = lo; base < hi; base += 32) {
      // gathers for both 16-edge tiles (clamped; masked via cmeta check)
      int e0 = base + n15;      if (e0 > hi - 1) e0 = hi - 1;
      int e1 = base + 16 + n15; if (e1 > hi - 1) e1 = hi - 1;
      int s0 = es[e0], s1 = es[e1];
      const short8* x0 = reinterpret_cast<const short8*>(xin + (size_t)s0 * 64);
      const short8* x1 = reinterpret_cast<const short8*>(xin + (size_t)s1 * 64);
      short8 a00 = x0[quad], a01 = x0[4 + quad];
      short8 a10 = x1[quad], a11 = x1[4 + quad];
      // indicator metadata for k = quad*8 + j (clamped read; validity masked)
      int kp = base + quad * 8;
      int mt[8];
#pragma unroll
      for (int j = 0; j < 8; ++j) {
        int rp = kp + j; if (rp > NEDGE - 1) rp = NEDGE - 1;
        mt[j] = cmeta[rp];
      }
      // edge transform MFMAs
      f32x4 ac0[4], ac1[4];
#pragma unroll
      for (int nb = 0; nb < 4; ++nb) {
        ac0[nb] = (f32x4){0.f, 0.f, 0.f, 0.f};
        ac1[nb] = (f32x4){0.f, 0.f, 0.f, 0.f};
      }
#pragma unroll
      for (int nb = 0; nb < 4; ++nb) {
        ac0[nb] = __builtin_amdgcn_mfma_f32_16x16x32_bf16(a00, bfr[nb][0], ac0[nb], 0, 0, 0);
        ac0[nb] = __builtin_amdgcn_mfma_f32_16x16x32_bf16(a01, bfr[nb][1], ac0[nb], 0, 0, 0);
        ac1[nb] = __builtin_amdgcn_mfma_f32_16x16x32_bf16(a10, bfr[nb][0], ac1[nb], 0, 0, 0);
        ac1[nb] = __builtin_amdgcn_mfma_f32_16x16x32_bf16(a11, bfr[nb][1], ac1[nb], 0, 0, 0);
      }
      // transpose to wave-private scratch: ms[dim*SCRP + edge], edges 0..31.
      // Lane holds (edge=quad*4+i, dim=nb*16+n15); pack 4 edges -> one b64.
#pragma unroll
      for (int nb = 0; nb < 4; ++nb) {
        int dim = nb * 16 + n15;
        unsigned int l0 = ((unsigned int)f2bf(ac0[nb][1]) << 16) | (unsigned int)f2bf(ac0[nb][0]);
        unsigned int h0 = ((unsigned int)f2bf(ac0[nb][3]) << 16) | (unsigned int)f2bf(ac0[nb][2]);
        unsigned int l1 = ((unsigned int)f2bf(ac1[nb][1]) << 16) | (unsigned int)f2bf(ac1[nb][0]);
        unsigned int h1 = ((unsigned int)f2bf(ac1[nb][3]) << 16) | (unsigned int)f2bf(ac1[nb][2]);
        uint2 p0; p0.x = l0; p0.y = h0;
        uint2 p1; p1.x = l1; p1.y = h1;
        *reinterpret_cast<uint2*>(ms + dim * SCRP + quad * 4) = p0;        // edges quad*4..+3
        *reinterpret_cast<uint2*>(ms + dim * SCRP + 16 + quad * 4) = p1;   // edges 16+quad*4..
      }
      __asm__ volatile("s_waitcnt lgkmcnt(0)" ::: "memory");  // cross-lane LDS RAW
      // B-frags: n=dim(lane&15 within nb), k=edge(quad*8+j) -> 16B aligned b128
      short8 Bf[4];
#pragma unroll
      for (int nb = 0; nb < 4; ++nb)
        Bf[nb] = *reinterpret_cast<const short8*>(ms + (nb * 16 + n15) * SCRP + quad * 8);
      // indicator MFMAs per dst-group
#pragma unroll
      for (int gr = 0; gr < 4; ++gr) {
        short8 Af;
#pragma unroll
        for (int j = 0; j < 8; ++j) {
          int mm = mt[j];
          bool ok = (kp + j < hi) && ((mm & 63) == gr * 16 + n15);
          Af[j] = ok ? (short)((unsigned int)mm >> 16) : (short)0;
        }
#pragma unroll
        for (int nb = 0; nb < 4; ++nb)
          D[gr][nb] = __builtin_amdgcn_mfma_f32_16x16x32_bf16(Af, Bf[nb], D[gr][nb], 0, 0, 0);
      }
    }
  }
  // cross-wave combine (serialized, no atomics). D C-layout: row=quad*4+i=m
  // (dst within group), col=n15=dim within nb.
  for (int w = 0; w < 4; ++w) {
    if (wv == w) {
#pragma unroll
      for (int gr = 0; gr < 4; ++gr)
#pragma unroll
        for (int nb = 0; nb < 4; ++nb)
#pragma unroll
          for (int i = 0; i < 4; ++i) {
            int a = (gr * 16 + quad * 4 + i) * 64 + nb * 16 + n15;
            if (w == 0) accL[a] = D[gr][nb][i];
            else accL[a] += D[gr][nb][i];
          }
    }
    __syncthreads();
  }
  // epilogue: 4 waves, one 16-node tile each (root GEMM + combine + bias)
  int basen = g * 64 + wv * 16;
  int gn = basen + n15;
  if (gn > N_NODES - 1) gn = N_NODES - 1;
  const short8* xr = reinterpret_cast<const short8*>(xin + (size_t)gn * 64);
  short8 a0 = xr[quad], a1 = xr[4 + quad];
  short8 rfr[4][2];
#pragma unroll
  for (int nb = 0; nb < 4; ++nb)
#pragma unroll
    for (int k = 0; k < 2; ++k)
      rfr[nb][k] = *reinterpret_cast<const short8*>(wrr + ((nb * 16 + n15) << 6) + k * 32 + quad * 8);
  f32x4 acc[4];
#pragma unroll
  for (int nb = 0; nb < 4; ++nb) acc[nb] = (f32x4){0.f, 0.f, 0.f, 0.f};
#pragma unroll
  for (int nb = 0; nb < 4; ++nb) {
    acc[nb] = __builtin_amdgcn_mfma_f32_16x16x32_bf16(a0, rfr[nb][0], acc[nb], 0, 0, 0);
    acc[nb] = __builtin_amdgcn_mfma_f32_16x16x32_bf16(a1, rfr[nb][1], acc[nb], 0, 0, 0);
  }
#pragma unroll
  for (int i = 0; i < 4; ++i) {
    int node = basen + quad * 4 + i;
    if (node < N_NODES) {
      int dl = wv * 16 + quad * 4 + i;
#pragma unroll
      for (int nb = 0; nb < 4; ++nb) {
        int col = nb * 16 + n15;
        float val = acc[nb][i] + accL[dl * 64 + col] + bias[col];
        if (mode == 0) {
          val = fmaxf(val, 0.f);
          xout[(size_t)node * 64 + col] = f2bf(val);
        } else {
          outf[(size_t)node * 64 + col] = val;
        }
      }
    }
  }
}

// ---- launcher ------------------------------------------------------------

extern "C" void kernel_launch(void* const* d_in, const int* in_sizes, int n_in,
                              void* d_out, int out_size, void* d_ws, size_t ws_size,
                              hipStream_t stream) {
  const float* x   = (const float*)d_in[0];
  const int*   ei  = (const int*)d_in[1];
  const int*   et  = (const int*)d_in[2];
  const float* w0  = (const float*)d_in[3];
  const float* wr0 = (const float*)d_in[4];
  const float* b0  = (const float*)d_in[5];
  const float* w1  = (const float*)d_in[6];
  const float* wr1 = (const float*)d_in[7];
  const float* b1  = (const float*)d_in[8];
  const float* w2  = (const float*)d_in[9];
  const float* wr2 = (const float*)d_in[10];
  const float* b2  = (const float*)d_in[11];
  float* out = (float*)d_out;

  char* p = (char*)d_ws;
  auto take = [&](size_t bytes) -> char* {
    char* q = p;
    p += (bytes + 255) & ~(size_t)255;
    return q;
  };
  // ccur + dcur + kcur adjacent: one memset clears all
  char*  zbase   = p;
  int*   ccur    = (int*)take(32 * 4);
  int*   dcur    = (int*)take((size_t)NCHUNK * 2048 * 4);
  int*   kcur    = (int*)take((size_t)NKEY2 * 4);
  size_t zbytes  = (size_t)(p - zbase);
  int*   key_off = (int*)take((size_t)(NKEY2 + 1) * 4);
  int*   dst_off = (int*)take((size_t)(N_NODES + 1) * 4);
  int*   psum    = (int*)take(256 * 4);
  int*   psb     = (int*)take(256 * 4);
  int2*  ce      = (int2*)take((size_t)NCHUNK * CAP * 8);    // 7.4 MB arenas
  int*   dkr     = (int*)take((size_t)NCHUNK * CAP * 4);     // 3.7 MB
  int*   es      = (int*)take((size_t)NEDGE * 4);
  unsigned char* dl8 = (unsigned char*)take((size_t)NEDGE);
  int*   rpr     = (int*)take((size_t)NEDGE * 4);
  int*   cmeta   = (int*)take((size_t)NEDGE * 4);
  unsigned short* xbfA = (unsigned short*)take((size_t)N_NODES * 64 * 2);
  unsigned short* xbfB = (unsigned short*)take((size_t)N_NODES * 64 * 2);
  unsigned short* Wt0 = (unsigned short*)take((size_t)NREL * 4096 * 2);
  unsigned short* Wt1 = (unsigned short*)take((size_t)NREL * 4096 * 2);
  unsigned short* Wt2 = (unsigned short*)take((size_t)NREL * 4096 * 2);
  unsigned short* Wr0 = (unsigned short*)take(4096 * 2);
  unsigned short* Wr1 = (unsigned short*)take(4096 * 2);
  unsigned short* Wr2 = (unsigned short*)take(4096 * 2);

  // preprocessing (edge structure shared by all 3 layers)
  hipMemsetAsync(zbase, 0, zbytes, stream);
  csort_k<<<NEDGE / 1280, 256, 0, stream>>>(ei, et, ccur, ce);
  dim3 mg(5, NCHUNK);                              // 5 tiles x 8192 covers CAP
  msplit_k<<<mg, 1024, 0, stream>>>(ce, ccur, dcur, kcur, dkr);
  kscan_k<<<1, 256, 0, stream>>>(kcur, key_off);
  dsA_k<<<256, 256, 0, stream>>>(dcur, psum);
  dsB_k<<<1, 256, 0, stream>>>(psum, psb, dst_off);
  dsC_k<<<256, 256, 0, stream>>>(dcur, psb, dst_off);
  place_k<<<mg, 1024, 0, stream>>>(ce, ccur, dkr, key_off, dst_off, es, dl8, rpr);
  coef_k<<<N_NODES / 8, 256, 0, stream>>>(rpr, dl8, dst_off, cmeta);
  prep_k<<<(NREL * 4096 + 255) / 256, 256, 0, stream>>>(w0, w1, w2, wr0, wr1, wr2,
                                                        Wt0, Wt1, Wt2, Wr0, Wr1, Wr2);

  const int conv_blocks = N_NODES * 64 / 256;      // 12500, exact
  conv_k<<<conv_blocks, 256, 0, stream>>>(x, xbfA);

  // fused layers (xbf double-buffered: A -> B -> A -> out)
  fuse_k<<<NSUB, 256, 0, stream>>>(xbfA, Wt0, Wr0, b0, es, cmeta, key_off,
                                   xbfB, nullptr, 0);
  fuse_k<<<NSUB, 256, 0, stream>>>(xbfB, Wt1, Wr1, b1, es, cmeta, key_off,
                                   xbfA, nullptr, 0);
  fuse_k<<<NSUB, 256, 0, stream>>>(xbfA, Wt2, Wr2, b2, es, cmeta, key_off,
                                   nullptr, out, 1);
}

// Round 20
// 379.901 us; speedup vs baseline: 1.2816x; 1.2816x over previous
//
#include <hip/hip_runtime.h>
#include <cstdint>
#include <cstddef>

#define N_NODES 50000
#define HDIM 64
#define NREL 50
#define NEDGE 800000
#define DCHUNK 196    // ceil(N_NODES/256)
#define CHUNKSH 11    // 2048 dsts per chunk
#define NCHUNK 25     // ceil(50000/2048)
#define NKEYS (NCHUNK * NREL)   // 1250 sort keys (chunk-major, rel-minor)
#define KCH 5         // keys per thread in kscan (256*5 = 1280 >= 1250)
#define CAP 36864     // arena capacity per chunk (expected 32768, ~27 sigma margin)
#define TILE 8192     // edges per msplit/place block (1024 thr x 8)

typedef __attribute__((ext_vector_type(8))) short short8;
typedef __attribute__((ext_vector_type(4))) float f32x4;

static __device__ __forceinline__ unsigned short f2bf(float f) {
  union { float f; unsigned int u; } v; v.f = f;
  unsigned int u = v.u;
  unsigned int r = (u + 0x7FFFu + ((u >> 16) & 1u)) >> 16;  // RNE
  return (unsigned short)r;
}

// ---- preprocessing: atomic-light two-level counting sort ------------------

__global__ __launch_bounds__(256) void csort_k(const int* __restrict__ ei,
                                               const int* __restrict__ et,
                                               int* __restrict__ ccur,
                                               int2* __restrict__ ce) {
  __shared__ int chist[32];
  __shared__ int cbase[32];
  int tid = threadIdx.x;
  if (tid < 32) chist[tid] = 0;
  __syncthreads();
  int ebase = blockIdx.x * 1280 + tid;          // 625 blocks x 1280 edges
  int src_[5], dr_[5], ch_[5], loc_[5];
#pragma unroll
  for (int i = 0; i < 5; ++i) {
    int e = ebase + i * 256;
    int src = ei[e];
    int dst = ei[NEDGE + e];
    int r = et[e];
    int ch = dst >> CHUNKSH;
    src_[i] = src;
    dr_[i] = (dst << 6) | r;
    ch_[i] = ch;
    loc_[i] = atomicAdd(&chist[ch], 1);         // LDS
  }
  __syncthreads();
  if (tid < NCHUNK && chist[tid] > 0)
    cbase[tid] = atomicAdd(&ccur[tid], chist[tid]);   // 25 returning/block
  __syncthreads();
#pragma unroll
  for (int i = 0; i < 5; ++i)
    ce[(size_t)ch_[i] * CAP + cbase[ch_[i]] + loc_[i]] = make_int2(src_[i], dr_[i]);
}

__global__ __launch_bounds__(1024) void msplit_k(const int2* __restrict__ ce,
                                                 const int* __restrict__ ccur,
                                                 int* __restrict__ dcur,
                                                 int* __restrict__ kcur,
                                                 int* __restrict__ dkr) {
  __shared__ int dhist[2048], dbase[2048];
  __shared__ int rhist[64], rbase[64];
  int c = blockIdx.y;
  int len = ccur[c];
  int t0 = blockIdx.x * TILE;
  if (t0 >= len) return;                        // block-uniform
  int tid = threadIdx.x;
  dhist[tid] = 0;
  dhist[tid + 1024] = 0;
  if (tid < 64) rhist[tid] = 0;
  __syncthreads();
  int n = min(TILE, len - t0);
  const int2* seg = ce + (size_t)c * CAP + t0;
  int pk[8], dr_[8];
#pragma unroll
  for (int k = 0; k < 8; ++k) {
    int j = tid + k * 1024;
    if (j < n) {
      int2 v = seg[j];
      dr_[k] = v.y;
      int d11 = (v.y >> 6) & 2047;
      int rel = v.y & 63;
      int dl = atomicAdd(&dhist[d11], 1);       // LDS
      int rl = atomicAdd(&rhist[rel], 1);       // LDS
      pk[k] = (dl << 16) | rl;
    } else {
      pk[k] = -1;
    }
  }
  __syncthreads();
  int h0 = dhist[tid];
  if (h0 > 0) dbase[tid] = atomicAdd(&dcur[(c << CHUNKSH) + tid], h0);
  int h1 = dhist[tid + 1024];
  if (h1 > 0) dbase[tid + 1024] = atomicAdd(&dcur[(c << CHUNKSH) + tid + 1024], h1);
  if (tid < NREL) {
    int hr = rhist[tid];
    if (hr > 0) rbase[tid] = atomicAdd(&kcur[c * NREL + tid], hr);
  }
  __syncthreads();
#pragma unroll
  for (int k = 0; k < 8; ++k) {
    if (pk[k] >= 0) {
      int d11 = (dr_[k] >> 6) & 2047;
      int rel = dr_[k] & 63;
      int drank = dbase[d11] + (pk[k] >> 16);
      int krank = rbase[rel] + (pk[k] & 0xFFFF);
      dkr[(size_t)c * CAP + t0 + tid + k * 1024] = (drank << 16) | krank;
    }
  }
}

__global__ __launch_bounds__(256) void kscan_k(const int* __restrict__ kcur,
                                               int* __restrict__ key_off) {
  __shared__ int a[256], bb[256];
  int t = threadIdx.x;
  int base = t * KCH;
  int local[KCH];
  int s = 0;
#pragma unroll
  for (int i = 0; i < KCH; ++i) {
    int k = base + i;
    int v = (k < NKEYS) ? kcur[k] : 0;
    local[i] = s;
    s += v;
  }
  a[t] = s;
  __syncthreads();
  bool flip = false;
  for (int off = 1; off < 256; off <<= 1) {
    int* c = flip ? bb : a;
    int* n = flip ? a : bb;
    int x = c[t];
    if (t >= off) x += c[t - off];
    n[t] = x;
    __syncthreads();
    flip = !flip;
  }
  int incl = (flip ? bb : a)[t];
  int excl = incl - s;
#pragma unroll
  for (int i = 0; i < KCH; ++i) {
    int k = base + i;
    if (k < NKEYS) key_off[k] = excl + local[i];
  }
  if (t == 255) key_off[NKEYS] = incl;          // == NEDGE
}

__global__ __launch_bounds__(256) void dsA_k(const int* __restrict__ dcnt,
                                             int* __restrict__ psum) {
  __shared__ int red[256];
  int t = threadIdx.x, b = blockIdx.x;
  int idx = b * DCHUNK + t;
  int v = (t < DCHUNK && idx < N_NODES) ? dcnt[idx] : 0;
  red[t] = v;
  __syncthreads();
  for (int s = 128; s > 0; s >>= 1) {
    if (t < s) red[t] += red[t + s];
    __syncthreads();
  }
  if (t == 0) psum[b] = red[0];
}

__global__ __launch_bounds__(256) void dsB_k(const int* __restrict__ psum,
                                             int* __restrict__ psb,
                                             int* __restrict__ dst_off) {
  __shared__ int a[256], bb[256];
  int t = threadIdx.x;
  int v = psum[t];
  a[t] = v;
  __syncthreads();
  bool flip = false;
  for (int off = 1; off < 256; off <<= 1) {
    int* c = flip ? bb : a;
    int* n = flip ? a : bb;
    int x = c[t];
    if (t >= off) x += c[t - off];
    n[t] = x;
    __syncthreads();
    flip = !flip;
  }
  int incl = (flip ? bb : a)[t];
  psb[t] = incl - v;
  if (t == 255) dst_off[N_NODES] = incl;
}

__global__ __launch_bounds__(256) void dsC_k(const int* __restrict__ dcnt,
                                             const int* __restrict__ psb,
                                             int* __restrict__ dst_off) {
  __shared__ int a[256], bb[256];
  int t = threadIdx.x, b = blockIdx.x;
  int idx = b * DCHUNK + t;
  int v = (t < DCHUNK && idx < N_NODES) ? dcnt[idx] : 0;
  a[t] = v;
  __syncthreads();
  bool flip = false;
  for (int off = 1; off < 256; off <<= 1) {
    int* c = flip ? bb : a;
    int* n = flip ? a : bb;
    int x = c[t];
    if (t >= off) x += c[t - off];
    n[t] = x;
    __syncthreads();
    flip = !flip;
  }
  int incl = (flip ? bb : a)[t];
  if (t < DCHUNK && idx < N_NODES) dst_off[idx] = psb[b] + (incl - v);
}

__global__ __launch_bounds__(1024) void place_k(const int2* __restrict__ ce,
                                                const int* __restrict__ ccur,
                                                const int* __restrict__ dkr,
                                                const int* __restrict__ key_off,
                                                const int* __restrict__ dst_off,
                                                int* __restrict__ es,
                                                int* __restrict__ rpr) {
  int c = blockIdx.y;
  int len = ccur[c];
  int t0 = blockIdx.x * TILE;
  if (t0 >= len) return;
  int tid = threadIdx.x;
  int n = min(TILE, len - t0);
  size_t base = (size_t)c * CAP + t0;
#pragma unroll
  for (int k = 0; k < 8; ++k) {
    int j = tid + k * 1024;
    if (j < n) {
      int2 v = ce[base + j];
      int dk = dkr[base + j];
      int dst = v.y >> 6;
      int rel = v.y & 63;
      int key = c * NREL + rel;
      int pos = key_off[key] + (dk & 0xFFFF);
      int dp = dst_off[dst] + (dk >> 16);
      es[pos] = v.x;
      rpr[dp] = (pos << 6) | rel;
    }
  }
}

// coefd[j] = 1 / #(edges in j's dst-segment with same rel); rel = rpr&63
__global__ __launch_bounds__(256) void coef_k(const int* __restrict__ rpr,
                                              const int* __restrict__ dst_off,
                                              float* __restrict__ coefd) {
  int lane = threadIdx.x & 63;
  int wv = (blockIdx.x * 256 + threadIdx.x) >> 6;
  int half = lane >> 5, l = lane & 31;
  int dst = wv * 2 + half;
  if (dst >= N_NODES) return;
  int lo = dst_off[dst], hi = dst_off[dst + 1];
  for (int j = lo + l; j < hi; j += 32) {
    int r = rpr[j] & 63;
    int c = 0;
    for (int k = lo; k < hi; ++k) c += ((rpr[k] & 63) == r);
    coefd[j] = 1.0f / (float)c;
  }
}

// weight prep: transpose to [r][o][d] bf16; expand block-diagonal to dense
__global__ void prep_k(const float* __restrict__ w0, const float* __restrict__ w1,
                       const float* __restrict__ w2,
                       const float* __restrict__ wr0f, const float* __restrict__ wr1f,
                       const float* __restrict__ wr2f,
                       unsigned short* __restrict__ Wt0, unsigned short* __restrict__ Wt1,
                       unsigned short* __restrict__ Wt2,
                       unsigned short* __restrict__ Wr0, unsigned short* __restrict__ Wr1,
                       unsigned short* __restrict__ Wr2) {
  int idx = blockIdx.x * 256 + threadIdx.x;
  if (idx < NREL * 4096) {
    int r = idx >> 12, rem = idx & 4095, d = rem >> 6, o = rem & 63;
    int tpos = (r << 12) + (o << 6) + d;        // [r][o][d]
    Wt2[tpos] = f2bf(w2[idx]);                  // w2 is [r][d][o]
    int b = o >> 4;
    float v0 = 0.f, v1 = 0.f;
    if (b == (d >> 4)) {
      int widx = ((r * 4 + b) * 16 + (d & 15)) * 16 + (o & 15);
      v0 = w0[widx];
      v1 = w1[widx];
    }
    Wt0[tpos] = f2bf(v0);
    Wt1[tpos] = f2bf(v1);
  }
  if (idx < 4096) {
    int d = idx >> 6, o = idx & 63;
    int tpos = (o << 6) + d;
    Wr0[tpos] = f2bf(wr0f[idx]);
    Wr1[tpos] = f2bf(wr1f[idx]);
    Wr2[tpos] = f2bf(wr2f[idx]);
  }
}

// fp32 -> bf16 convert (layer-0 input only)
__global__ void conv_k(const float* __restrict__ in, unsigned short* __restrict__ out) {
  int i = blockIdx.x * 256 + threadIdx.x;
  out[i] = f2bf(in[i]);
}

// ---- per-layer kernels ---------------------------------------------------
// Round-11 operand order (A=edges, B=weights). C/D: col=lane&15 (out-dim),
// row=quad*4+i (edge in tile).

// h[n,:] = bias + x[n,:] @ w_root
__global__ __launch_bounds__(256) void root_k(const unsigned short* __restrict__ xbf,
                                              const unsigned short* __restrict__ wr,
                                              const float* __restrict__ bias,
                                              float* __restrict__ out) {
  int wid = threadIdx.x >> 6, lane = threadIdx.x & 63;
  int n15 = lane & 15, quad = lane >> 4;
  int t = blockIdx.x * 4 + wid;
  if (t >= N_NODES / 16) return;
  short8 bfr[4][2];
#pragma unroll
  for (int nb = 0; nb < 4; ++nb)
#pragma unroll
    for (int k = 0; k < 2; ++k)
      bfr[nb][k] = *reinterpret_cast<const short8*>(wr + ((nb * 16 + n15) << 6) + k * 32 + quad * 8);
  float bv[4];
#pragma unroll
  for (int nb = 0; nb < 4; ++nb) bv[nb] = bias[nb * 16 + n15];

  int base = t * 16;
  const short8* xr = reinterpret_cast<const short8*>(xbf + (size_t)(base + n15) * 64);
  short8 a0 = xr[quad], a1 = xr[4 + quad];
  f32x4 acc[4];
#pragma unroll
  for (int nb = 0; nb < 4; ++nb) acc[nb] = (f32x4){0.f, 0.f, 0.f, 0.f};
#pragma unroll
  for (int nb = 0; nb < 4; ++nb) {
    acc[nb] = __builtin_amdgcn_mfma_f32_16x16x32_bf16(a0, bfr[nb][0], acc[nb], 0, 0, 0);
    acc[nb] = __builtin_amdgcn_mfma_f32_16x16x32_bf16(a1, bfr[nb][1], acc[nb], 0, 0, 0);
  }
#pragma unroll
  for (int i = 0; i < 4; ++i) {
    int node = base + quad * 4 + i;
#pragma unroll
    for (int nb = 0; nb < 4; ++nb)
      out[(size_t)node * 64 + nb * 16 + n15] = acc[nb][i] + bv[nb];
  }
}

// msg[e,:] = x[src_e,:] @ W_rel  -- rows in (chunk,rel)-sorted order:
// sequential CACHED stores (L2 write-combining; NT stores regressed, r16).
__global__ __launch_bounds__(256) void edge_k(const unsigned short* __restrict__ xbf,
                                              const unsigned short* __restrict__ wt,
                                              const int* __restrict__ es,
                                              const int* __restrict__ key_off,
                                              unsigned short* __restrict__ msg) {
  int key = blockIdx.y;
  int lo = key_off[key], hi = key_off[key + 1];
  if (lo >= hi) return;
  int wid = threadIdx.x >> 6, lane = threadIdx.x & 63;
  int n15 = lane & 15, quad = lane >> 4;
  const unsigned short* wr = wt + ((size_t)(key % NREL) << 12);
  short8 bfr[4][2];
#pragma unroll
  for (int nb = 0; nb < 4; ++nb)
#pragma unroll
    for (int k = 0; k < 2; ++k)
      bfr[nb][k] = *reinterpret_cast<const short8*>(wr + ((nb * 16 + n15) << 6) + k * 32 + quad * 8);

  int ntiles = (hi - lo + 15) >> 4;
  for (int t = blockIdx.x * 4 + wid; t < ntiles; t += gridDim.x * 4) {
    int base = lo + t * 16;
    int eidx = base + n15;
    if (eidx > NEDGE - 1) eidx = NEDGE - 1;     // safe read; store guards validity
    int src = es[eidx];
    const short8* xr = reinterpret_cast<const short8*>(xbf + (size_t)src * 64);
    short8 a0 = xr[quad], a1 = xr[4 + quad];
    f32x4 acc[4];
#pragma unroll
    for (int nb = 0; nb < 4; ++nb) acc[nb] = (f32x4){0.f, 0.f, 0.f, 0.f};
#pragma unroll
    for (int nb = 0; nb < 4; ++nb) {
      acc[nb] = __builtin_amdgcn_mfma_f32_16x16x32_bf16(a0, bfr[nb][0], acc[nb], 0, 0, 0);
      acc[nb] = __builtin_amdgcn_mfma_f32_16x16x32_bf16(a1, bfr[nb][1], acc[nb], 0, 0, 0);
    }
#pragma unroll
    for (int i = 0; i < 4; ++i) {
      int e2 = base + quad * 4 + i;
      if (e2 < hi) {
        size_t row = (size_t)e2 * 64;
#pragma unroll
        for (int nb = 0; nb < 4; ++nb)
          msg[row + nb * 16 + n15] = f2bf(acc[nb][i]);
      }
    }
  }
}

// out[dst,:] = h[dst,:] + sum coefd[j]*msg[rpr[j]>>6,:]
// msg/h reads NON-TEMPORAL (single-use streams; keeps xbf L2-resident).
__global__ __launch_bounds__(256) void agg_k(const float* __restrict__ h,
                                             const unsigned short* __restrict__ msg,
                                             const float* __restrict__ coefd,
                                             const int* __restrict__ rpr,
                                             const int* __restrict__ dst_off,
                                             float* __restrict__ outf,
                                             unsigned short* __restrict__ outbf,
                                             int mode) {
  int lane = threadIdx.x & 63;
  int wv = (blockIdx.x * 256 + threadIdx.x) >> 6;
  int half = lane >> 5, l = lane & 31;
  int dst = wv * 2 + half;
  if (dst >= N_NODES) return;
  int lo = dst_off[dst], hi = dst_off[dst + 1];
  float ax = __builtin_nontemporal_load(h + (size_t)dst * 64 + 2 * l);
  float ay = __builtin_nontemporal_load(h + (size_t)dst * 64 + 2 * l + 1);
  const unsigned int* m32 = reinterpret_cast<const unsigned int*>(msg);
  int j = lo;
  for (; j + 4 <= hi; j += 4) {
    int q0 = rpr[j] >> 6, q1 = rpr[j + 1] >> 6, q2 = rpr[j + 2] >> 6, q3 = rpr[j + 3] >> 6;
    float c0 = coefd[j], c1 = coefd[j + 1], c2 = coefd[j + 2], c3 = coefd[j + 3];
    unsigned int u0 = __builtin_nontemporal_load(m32 + q0 * 32 + l);
    unsigned int u1 = __builtin_nontemporal_load(m32 + q1 * 32 + l);
    unsigned int u2 = __builtin_nontemporal_load(m32 + q2 * 32 + l);
    unsigned int u3 = __builtin_nontemporal_load(m32 + q3 * 32 + l);
    union { unsigned int u; float f; } cx, cy;
    cx.u = (u0 & 0xFFFFu) << 16; cy.u = u0 & 0xFFFF0000u; ax += c0 * cx.f; ay += c0 * cy.f;
    cx.u = (u1 & 0xFFFFu) << 16; cy.u = u1 & 0xFFFF0000u; ax += c1 * cx.f; ay += c1 * cy.f;
    cx.u = (u2 & 0xFFFFu) << 16; cy.u = u2 & 0xFFFF0000u; ax += c2 * cx.f; ay += c2 * cy.f;
    cx.u = (u3 & 0xFFFFu) << 16; cy.u = u3 & 0xFFFF0000u; ax += c3 * cx.f; ay += c3 * cy.f;
  }
  for (; j < hi; ++j) {
    float c = coefd[j];
    int pos = rpr[j] >> 6;
    unsigned int u = __builtin_nontemporal_load(m32 + pos * 32 + l);
    union { unsigned int u; float f; } cx, cy;
    cx.u = (u & 0xFFFFu) << 16;
    cy.u = u & 0xFFFF0000u;
    ax += c * cx.f;
    ay += c * cy.f;
  }
  if (mode == 0) {
    float fx = fmaxf(ax, 0.f), fy = fmaxf(ay, 0.f);
    unsigned int pk = ((unsigned int)f2bf(fy) << 16) | (unsigned int)f2bf(fx);
    *reinterpret_cast<unsigned int*>(outbf + (size_t)dst * 64 + 2 * l) = pk;
  } else {
    float2 o2; o2.x = ax; o2.y = ay;
    *reinterpret_cast<float2*>(outf + (size_t)dst * 64 + 2 * l) = o2;
  }
}

// ---- launcher ------------------------------------------------------------

extern "C" void kernel_launch(void* const* d_in, const int* in_sizes, int n_in,
                              void* d_out, int out_size, void* d_ws, size_t ws_size,
                              hipStream_t stream) {
  const float* x   = (const float*)d_in[0];
  const int*   ei  = (const int*)d_in[1];
  const int*   et  = (const int*)d_in[2];
  const float* w0  = (const float*)d_in[3];
  const float* wr0 = (const float*)d_in[4];
  const float* b0  = (const float*)d_in[5];
  const float* w1  = (const float*)d_in[6];
  const float* wr1 = (const float*)d_in[7];
  const float* b1  = (const float*)d_in[8];
  const float* w2  = (const float*)d_in[9];
  const float* wr2 = (const float*)d_in[10];
  const float* b2  = (const float*)d_in[11];
  float* out = (float*)d_out;

  char* p = (char*)d_ws;
  auto take = [&](size_t bytes) -> char* {
    char* q = p;
    p += (bytes + 255) & ~(size_t)255;
    return q;
  };
  // ccur + dcur + kcur are kept adjacent so one memset clears all three.
  char*  zbase   = p;
  int*   ccur    = (int*)take(32 * 4);
  int*   dcur    = (int*)take((size_t)NCHUNK * 2048 * 4);
  int*   kcur    = (int*)take((size_t)NKEYS * 4);
  size_t zbytes  = (size_t)(p - zbase);
  int*   key_off = (int*)take((size_t)(NKEYS + 1) * 4);
  int*   dst_off = (int*)take((size_t)(N_NODES + 1) * 4);
  int*   psum    = (int*)take(256 * 4);
  int*   psb     = (int*)take(256 * 4);
  int2*  ce      = (int2*)take((size_t)NCHUNK * CAP * 8);    // 7.4 MB arenas
  int*   dkr     = (int*)take((size_t)NCHUNK * CAP * 4);     // 3.7 MB
  int*   es      = (int*)take((size_t)NEDGE * 4);
  int*   rpr     = (int*)take((size_t)NEDGE * 4);
  float* coefd   = (float*)take((size_t)NEDGE * 4);
  unsigned short* xbf = (unsigned short*)take((size_t)N_NODES * 64 * 2);
  float* h       = (float*)take((size_t)N_NODES * 64 * 4);
  unsigned short* msg = (unsigned short*)take((size_t)NEDGE * 64 * 2);  // 102.4 MB
  unsigned short* Wt0 = (unsigned short*)take((size_t)NREL * 4096 * 2);
  unsigned short* Wt1 = (unsigned short*)take((size_t)NREL * 4096 * 2);
  unsigned short* Wt2 = (unsigned short*)take((size_t)NREL * 4096 * 2);
  unsigned short* Wr0 = (unsigned short*)take(4096 * 2);
  unsigned short* Wr1 = (unsigned short*)take(4096 * 2);
  unsigned short* Wr2 = (unsigned short*)take(4096 * 2);

  // preprocessing (edge structure shared by all 3 layers)
  hipMemsetAsync(zbase, 0, zbytes, stream);        // ccur + dcur + kcur
  csort_k<<<NEDGE / 1280, 256, 0, stream>>>(ei, et, ccur, ce);
  dim3 mg(5, NCHUNK);                              // 5 tiles x 8192 covers CAP
  msplit_k<<<mg, 1024, 0, stream>>>(ce, ccur, dcur, kcur, dkr);
  kscan_k<<<1, 256, 0, stream>>>(kcur, key_off);
  dsA_k<<<256, 256, 0, stream>>>(dcur, psum);
  dsB_k<<<1, 256, 0, stream>>>(psum, psb, dst_off);
  dsC_k<<<256, 256, 0, stream>>>(dcur, psb, dst_off);
  place_k<<<mg, 1024, 0, stream>>>(ce, ccur, dkr, key_off, dst_off, es, rpr);
  coef_k<<<N_NODES / 8, 256, 0, stream>>>(rpr, dst_off, coefd);
  prep_k<<<(NREL * 4096 + 255) / 256, 256, 0, stream>>>(w0, w1, w2, wr0, wr1, wr2,
                                                        Wt0, Wt1, Wt2, Wr0, Wr1, Wr2);

  const int conv_blocks = N_NODES * 64 / 256;      // 12500, exact
  const int root_blocks = (N_NODES / 16 + 3) / 4;  // 782
  const int agg_blocks  = N_NODES / 8;             // 6250: 4 waves/block x 2 dst/wave
  dim3 eg(2, NKEYS);                               // 8 waves per key segment

  // layer 0
  conv_k<<<conv_blocks, 256, 0, stream>>>(x, xbf);
  root_k<<<root_blocks, 256, 0, stream>>>(xbf, Wr0, b0, h);
  edge_k<<<eg, 256, 0, stream>>>(xbf, Wt0, es, key_off, msg);
  agg_k<<<agg_blocks, 256, 0, stream>>>(h, msg, coefd, rpr, dst_off, nullptr, xbf, 0);
  // layer 1
  root_k<<<root_blocks, 256, 0, stream>>>(xbf, Wr1, b1, h);
  edge_k<<<eg, 256, 0, stream>>>(xbf, Wt1, es, key_off, msg);
  agg_k<<<agg_blocks, 256, 0, stream>>>(h, msg, coefd, rpr, dst_off, nullptr, xbf, 0);
  // layer 2 (no ReLU, fp32 out)
  root_k<<<root_blocks, 256, 0, stream>>>(xbf, Wr2, b2, h);
  edge_k<<<eg, 256, 0, stream>>>(xbf, Wt2, es, key_off, msg);
  agg_k<<<agg_blocks, 256, 0, stream>>>(h, msg, coefd, rpr, dst_off, out, nullptr, 1);
}